// Round 16
// baseline (74.260 us; speedup 1.0000x reference)
//
#include <hip/hip_runtime.h>
#include <cstdint>
#include <math.h>

#define NP 9216     // 96*96
#define NP2 2304    // 48*48
#define KH 12       // harmonics k=0..12 (I_13(1)~1e-12: exact in fp32)
#define NMOM 78     // 13 * 6
#define MPITCH 84   // msh row pitch (bank-spread: 84%32=20 -> 8 distinct banks)

__device__ __forceinline__ float gelu_ex(float v){
  return 0.5f*v*(1.0f+erff(v*0.70710678118654752440f));
}
__device__ __forceinline__ float sigm(float v){
  return 1.0f/(1.0f+__expf(-v));
}

// K1: channel-LN over C=32 per pixel + sq1 1x1 conv (32->8)
__global__ __launch_bounds__(256) void k_ln1(const float* __restrict__ x,
    const float* __restrict__ lw, const float* __restrict__ lb,
    const float* __restrict__ sw, const float* __restrict__ sb,
    float* __restrict__ xn, float* __restrict__ z1)
{
  __shared__ float sred[2][8][32];
  __shared__ float xnsh[32][33];
  int p = threadIdx.x & 31, sl = threadIdx.x >> 5;
  int pix = blockIdx.x*32 + p;
  int b = pix / NP, n = pix % NP;
  const float* xp = x + (size_t)b*32*NP + (size_t)(sl*4)*NP + n;
  float v[4]; float s=0.f, s2=0.f;
#pragma unroll
  for (int c=0;c<4;c++){ float t=xp[(size_t)c*NP]; v[c]=t; s+=t; s2+=t*t; }
  sred[0][sl][p]=s; sred[1][sl][p]=s2;
  __syncthreads();
  s=0.f; s2=0.f;
#pragma unroll
  for (int g=0;g<8;g++){ s += sred[0][g][p]; s2 += sred[1][g][p]; }
  float mu = s*(1.f/32.f);
  float var = s2*(1.f/32.f)-mu*mu;
  float rs = rsqrtf(var+1e-5f);
  float* xo = xn + (size_t)b*32*NP + (size_t)(sl*4)*NP + n;
#pragma unroll
  for (int c=0;c<4;c++){
    int cc = sl*4+c;
    float t = (v[c]-mu)*rs*lw[cc]+lb[cc];
    xo[(size_t)c*NP] = t;
    xnsh[p][cc] = t;
  }
  __syncthreads();
  float vv[32];
#pragma unroll
  for (int c=0;c<32;c++) vv[c]=xnsh[p][c];
  int g = sl;
  float a = sb[g];
#pragma unroll
  for (int c=0;c<32;c++) a += vv[c]*sw[g*32+c];
  z1[(size_t)b*8*NP + (size_t)g*NP + n] = a;
}

// Phase B: cab1 (blocks 0..575) || sq2 (blocks 576..719)
__global__ __launch_bounds__(256) void k_phB(const float* __restrict__ xn,
    const float* __restrict__ w1, const float* __restrict__ b1,
    const float* __restrict__ z1, const float* __restrict__ w2,
    const float* __restrict__ b2,
    float* __restrict__ c1, float* __restrict__ u, float* __restrict__ spart)
{
  if (blockIdx.x < 576){
    int og = blockIdx.x/72, pb = blockIdx.x%72;
    int idx = pb*256+threadIdx.x;
    int b = idx/NP, n = idx%NP, i = n/96, j = n%96;
    float acc = b1[og];
    const float* xb = xn + (size_t)b*32*NP;
    const float* wb = w1 + og*288;
#pragma unroll
    for (int di=0;di<3;di++){
      int ii=i+di-1; if ((unsigned)ii>=96u) continue;
#pragma unroll
      for (int dj=0;dj<3;dj++){
        int jj=j+dj-1; if ((unsigned)jj>=96u) continue;
        const float* xp = xb + ii*96+jj;
        const float* wp = wb + di*3+dj;
#pragma unroll
        for (int c=0;c<32;c++) acc += xp[(size_t)c*NP]*wp[c*9];
      }
    }
    c1[(size_t)b*8*NP + (size_t)og*NP + n] = gelu_ex(acc);
  } else {
    __shared__ float red[4][5];
    int u2 = blockIdx.x-576;
    int pr = u2/18, pb = u2%18;
    int idx = pb*256+threadIdx.x;
    int b = idx/NP2, n = idx%NP2, i = n/48, j = n%48;
    int ocA = pr, ocB = pr+8;           // cp = 2*pr, 2*pr+1
    int gA = ocA>>1, gB = ocB>>1;
    const float* zpA = z1 + ((size_t)b*8+gA)*NP + (size_t)(2*i)*96 + 2*j;
    const float* zpB = z1 + ((size_t)b*8+gB)*NP + (size_t)(2*i)*96 + 2*j;
    float vA = zpA[0]*w2[ocA*4]+zpA[1]*w2[ocA*4+1]+zpA[96]*w2[ocA*4+2]+zpA[97]*w2[ocA*4+3]+b2[ocA];
    float vB = zpB[0]*w2[ocB*4]+zpB[1]*w2[ocB*4+1]+zpB[96]*w2[ocB*4+2]+zpB[97]*w2[ocB*4+3]+b2[ocB];
    u[((size_t)b*16+2*pr)*NP2 + n]   = vA;
    u[((size_t)b*16+2*pr+1)*NP2 + n] = vB;
    int wv=threadIdx.x>>6, ln=threadIdx.x&63;
    float st[5]={vA,vB,vA*vA,vB*vB,vA*vB};
#pragma unroll
    for (int k=0;k<5;k++){
      float r=st[k];
#pragma unroll
      for (int m=1;m<64;m<<=1) r+=__shfl_xor(r,m,64);
      if (ln==0) red[wv][k]=r;
    }
    __syncthreads();
    if (threadIdx.x<5){
      float r = red[0][threadIdx.x]+red[1][threadIdx.x]+red[2][threadIdx.x]+red[3][threadIdx.x];
      spart[(b*9 + (pb%9))*40 + pr*5 + threadIdx.x] = r;
    }
  }
}

// Phase C: cab2 (blocks 0..575) || qkmom (blocks 576..863)
__global__ __launch_bounds__(256) void k_phC(const float* __restrict__ c1,
    const float* __restrict__ w2, const float* __restrict__ b2,
    float* __restrict__ cbuf, float* __restrict__ ypart,
    const float* __restrict__ u, const float* __restrict__ spart,
    const float* __restrict__ cqw, const float* __restrict__ cqb,
    const float* __restrict__ cat, const float* __restrict__ cfw,
    const float* __restrict__ cfb,
    const float* __restrict__ qw, const float* __restrict__ qb,
    float2* __restrict__ qarr, float* __restrict__ mompart)
{
  if (blockIdx.x < 576){
    __shared__ float red[4][4];
    int og = blockIdx.x/72, pb = blockIdx.x%72;
    int idx = pb*256+threadIdx.x;
    int b = idx/NP, n = idx%NP, i = n/96, j = n%96;
    float acc[4];
#pragma unroll
    for (int k=0;k<4;k++) acc[k]=b2[og*4+k];
    const float* cb = c1 + (size_t)b*8*NP;
#pragma unroll
    for (int di=0;di<3;di++){
      int ii=i+di-1; if ((unsigned)ii>=96u) continue;
#pragma unroll
      for (int dj=0;dj<3;dj++){
        int jj=j+dj-1; if ((unsigned)jj>=96u) continue;
        const float* xp = cb + ii*96+jj;
#pragma unroll
        for (int c=0;c<8;c++){
          float val = xp[(size_t)c*NP];
          const float* wp = w2 + (og*4)*72 + c*9+di*3+dj;
#pragma unroll
          for (int k=0;k<4;k++) acc[k] += val*wp[k*72];
        }
      }
    }
    int wv = threadIdx.x>>6, ln = threadIdx.x&63;
#pragma unroll
    for (int k=0;k<4;k++){
      cbuf[(size_t)b*32*NP + (size_t)(og*4+k)*NP + n] = acc[k];
      float r = acc[k];
#pragma unroll
      for (int m=1;m<64;m<<=1) r += __shfl_xor(r, m, 64);
      if (ln==0) red[wv][k]=r;
    }
    __syncthreads();
    if (threadIdx.x<4){
      float r = red[0][threadIdx.x]+red[1][threadIdx.x]+red[2][threadIdx.x]+red[3][threadIdx.x];
      ypart[(og*72+pb)*4 + threadIdx.x] = r;
    }
  } else {
    __shared__ float red16[16][80];
    int u2 = blockIdx.x-576;
    int bh = u2/9, ch = u2%9;
    int n = ch*256 + threadIdx.x;
    int b = bh>>4, h = bh&15;
    int p = h&7, s = h>>3;
    int cc0=2*p, cc1=2*p+1;
    int oc0 = 2*(cc0&7)+(cc0>>3);   // NIDX
    int oc1 = 2*(cc1&7)+(cc1>>3);
    float AA[2], BB[2], CCc[2];
#pragma unroll
    for (int t2=0;t2<2;t2++){
      int oc = t2? oc1:oc0;
      int p2 = oc>>1, dd = oc&1;
      float st[5]={0,0,0,0,0};
      for (int ib=0; ib<9; ib++){
#pragma unroll
        for (int k=0;k<5;k++) st[k] += spart[(b*9+ib)*40 + p2*5 + k];
      }
      float S0=st[0],S1=st[1],Q00=st[2],Q11=st[3],Q01=st[4];
      float Sd = dd? S1:S0;
      float Qdd = dd? Q11:Q00;
      float cu0[2],cu1[2],ccst[2];
#pragma unroll
      for (int hh=0;hh<2;hh++){
        int h2=p2+8*hh;
        float th2=cat[h2];
        float aq=cqw[(2*p2+dd)*6+hh], bq=cqb[(2*p2+dd)*6+hh];
        float nq=fmaxf(sqrtf(fmaxf(aq*aq*Qdd+2.f*aq*bq*Sd+2304.f*bq*bq,0.f)),1e-12f);
        float m2[2],av[2],bv[2];
#pragma unroll
        for (int e=0;e<2;e++){
          float Se_=e?S1:S0, Qee=e?Q11:Q00, Qde=(dd==e)?Qdd:Q01;
          float ak=cqw[(2*p2+e)*6+2+hh], bk=cqb[(2*p2+e)*6+2+hh];
          float nk=fmaxf(sqrtf(fmaxf(ak*ak*Qee+2.f*ak*bk*Se_+2304.f*bk*bk,0.f)),1e-12f);
          float D=aq*ak*Qde + aq*bk*Sd + bq*ak*Se_ + 2304.f*bq*bk;
          m2[e]=th2*D/(nq*nk);
          av[e]=cqw[(2*p2+e)*6+4+hh]; bv[e]=cqb[(2*p2+e)*6+4+hh];
        }
        float mx=fmaxf(m2[0],m2[1]);
        float e0=__expf(m2[0]-mx), e1=__expf(m2[1]-mx);
        float inv=1.f/(e0+e1);
        cu0[hh]=e0*inv*av[0]; cu1[hh]=e1*inv*av[1]; ccst[hh]=e0*inv*bv[0]+e1*inv*bv[1];
      }
      float f0=cfw[oc*2], f1=cfw[oc*2+1];
      AA[t2]=f0*cu0[0]+f1*cu0[1];
      BB[t2]=f0*cu1[0]+f1*cu1[1];
      CCc[t2]=f0*ccst[0]+f1*ccst[1]+cfb[oc];
    }
    const float* u00 = u + ((size_t)b*16 + (oc0>>1)*2)*NP2;
    const float* u01 = u00 + NP2;
    const float* u10 = u + ((size_t)b*16 + (oc1>>1)*2)*NP2;
    const float* u11 = u10 + NP2;
    float w0 = AA[0]*u00[n]+BB[0]*u01[n]+CCc[0];
    float w1 = AA[1]*u10[n]+BB[1]*u11[n]+CCc[1];
    float k0 = qw[cc0*6+2+s]*w0+qb[cc0*6+2+s];
    float k1 = qw[cc1*6+2+s]*w1+qb[cc1*6+2+s];
    float rnk = 1.f/fmaxf(sqrtf(k0*k0+k1*k1),1e-12f);
    float kc = k0*rnk, ks = k1*rnk;      // (cos beta, sin beta)
    float q0 = qw[cc0*6+s]*w0+qb[cc0*6+s];
    float q1 = qw[cc1*6+s]*w1+qb[cc1*6+s];
    float rnq = 1.f/fmaxf(sqrtf(q0*q0+q1*q1),1e-12f);
    qarr[bh*NP2+n] = make_float2(q0*rnq, q1*rnq);

    int grp = threadIdx.x>>4, gl = threadIdx.x&15;
    float c = 1.f, sn = 0.f;
#pragma unroll
    for (int k=0;k<=KH;k++){
      float vals[6] = {c, sn, c*w0, sn*w0, c*w1, sn*w1};
#pragma unroll
      for (int jv=0;jv<6;jv++){
        float r = vals[jv];
        r += __shfl_xor(r, 1, 64);
        r += __shfl_xor(r, 2, 64);
        r += __shfl_xor(r, 4, 64);
        r += __shfl_xor(r, 8, 64);
        if (gl==0) red16[grp][k*6+jv] = r;
      }
      float cn = c*kc - sn*ks;
      sn = sn*kc + c*ks;
      c = cn;
    }
    __syncthreads();
    if (threadIdx.x < NMOM){
      float r = 0.f;
#pragma unroll
      for (int g=0;g<16;g++) r += red16[g][threadIdx.x];
      mompart[(bh*9+ch)*NMOM + threadIdx.x] = r;
    }
  }
}

// K9: quad-aligned fused kernel: moments+Bessel (block prologue), 1 Fourier chain
// per thread (128 chains = 8 quads x 8 groups x 2 heads), softmax finish, fuse,
// un1 via LDS tables, then SE + un2 1x1 + residual + LN2 + da_w1.
// Block tile = 2 rows x 16 cols (b, ri, cj); grid = 2*48*6 = 576.
__global__ __launch_bounds__(256) void k_un2(
    const float* __restrict__ mompart, const float2* __restrict__ qarr,
    const float* __restrict__ sat,
    const float* __restrict__ qw, const float* __restrict__ qb,
    const float* __restrict__ fw, const float* __restrict__ fb,
    const float* __restrict__ u1w, const float* __restrict__ u1b,
    const float* __restrict__ ypart,
    const float* __restrict__ aw1, const float* __restrict__ ab1,
    const float* __restrict__ aw2, const float* __restrict__ ab2,
    const float* __restrict__ u2w, const float* __restrict__ u2b,
    const float* __restrict__ x, const float* __restrict__ cbuf,
    const float* __restrict__ lw, const float* __restrict__ lb,
    const float* __restrict__ dw1, const float* __restrict__ db1,
    float* __restrict__ xsum, float* __restrict__ d1)
{
  __shared__ float msh[16*MPITCH];   // scaled moments, padded pitch
  __shared__ float fsh[16][13];      // Bessel factors
  __shared__ float osh[256];         // [qd][g][hh][2]
  __shared__ float pgsh[256];        // [qd][g][k]
  __shared__ float sred[2][8][32];
  __shared__ float xsh[32][33];
  __shared__ float y2sh[32];
  int tid = threadIdx.x;
  int bid = blockIdx.x;
  int b = bid/288; int rem = bid%288;
  int ri = rem/6, cj = rem%6;        // quad-row, col-group (16 cols)
  // --- prologue: Bessel factors (16 heads x 13), moment combine, SE ---
  if (tid < 208){
    int h = tid/13, k = tid%13;
    double t = (double)sat[h];
    double fac;
    if (fabs(t) < 1e-3){
      double xh = 0.5*t;
      double pk = 1.0;
      for (int q=1;q<=k;q++) pk *= xh/(double)q;
      double Ik = pk*(1.0 + xh*xh/(double)(k+1));
      fac = (k? 2.0:1.0)*Ik;
    } else {
      const int KS = 36;
      double ip1 = 0.0, ik = 1e-280, sum2 = 0.0;
      double vk = 0.0, v0 = 0.0;
      for (int q=KS; q>=1; --q){
        if (q == k) vk = ik;
        sum2 += ik;
        double im1 = ip1 + (2.0*(double)q/t)*ik;
        ip1 = ik; ik = im1;
      }
      v0 = ik;
      if (k == 0) vk = v0;
      double total = v0 + 2.0*sum2;
      double scale = exp(t)/total;
      fac = (k? 2.0:1.0)*vk*scale;
    }
    fsh[h][k] = (float)fac;
  }
  for (int e = tid; e < 16*NMOM; e += 256){
    int bh = e/NMOM, jj = e%NMOM;
    float ssum = 0.f;
    for (int ib=0; ib<9; ib++)
      ssum += mompart[((size_t)(b*16+bh)*9+ib)*NMOM + jj];
    msh[bh*MPITCH + jj] = ssum;
  }
  if (tid < 32){
    int c = tid;
    float ssum = 0.f;
    for (int ib=0; ib<36; ib++)
      ssum += ypart[((c>>2)*72 + b*36 + ib)*4 + (c&3)];
    float pr = ssum*(1.f/9216.f)*aw1[c];
#pragma unroll
    for (int m=1;m<32;m<<=1) pr += __shfl_xor(pr, m, 64);
    float y1 = fmaxf(pr+ab1[0], 0.f);
    y2sh[c] = sigm(aw2[c]*y1+ab2[c]);
  }
  __syncthreads();
  for (int e = tid; e < 16*NMOM; e += 256){
    int bh = e/NMOM, jj = e%NMOM;
    msh[bh*MPITCH + jj] *= fsh[bh][jj/6];
  }
  __syncthreads();
  // --- chain phase: 128 threads, 1 Fourier chain each ---
  if (tid < 128){
    int qd = tid & 7, g = (tid>>3)&7, hh = tid>>6;
    int h = g + 8*hh;
    int n48 = ri*48 + cj*8 + qd;
    float2 q = qarr[(size_t)(b*16+h)*NP2 + n48];
    const float* mrow = &msh[h*MPITCH];
    float c = 1.f, sn = 0.f;
    float Se=0.f, S0=0.f, S1=0.f;
#pragma unroll
    for (int k=0;k<=KH;k++){
      const float* mk = mrow + k*6;
      Se += c*mk[0] + sn*mk[1];
      S0 += c*mk[2] + sn*mk[3];
      S1 += c*mk[4] + sn*mk[5];
      float cn = c*q.x - sn*q.y;
      sn = sn*q.x + c*q.y;
      c = cn;
    }
    float rSe = 1.f/Se;
    float av0=qw[(2*g)*6+4+hh],  bv0=qb[(2*g)*6+4+hh];
    float av1=qw[(2*g+1)*6+4+hh],bv1=qb[(2*g+1)*6+4+hh];
    osh[((qd*8+g)*2+hh)*2+0] = av0*S0*rSe+bv0;
    osh[((qd*8+g)*2+hh)*2+1] = av1*S1*rSe+bv1;
  }
  __syncthreads();
  // --- fuse + un1 tables: 64 threads ---
  if (tid < 64){
    int qd = tid & 7, g = tid>>3;
    float o00 = osh[((qd*8+g)*2+0)*2+0];
    float o01 = osh[((qd*8+g)*2+0)*2+1];
    float o10 = osh[((qd*8+g)*2+1)*2+0];
    float o11 = osh[((qd*8+g)*2+1)*2+1];
    float zz0 = o00*fw[(2*g)*2]   + o10*fw[(2*g)*2+1]   + fb[2*g];
    float zz1 = o01*fw[(2*g+1)*2] + o11*fw[(2*g+1)*2+1] + fb[2*g+1];
#pragma unroll
    for (int k=0;k<4;k++){
      int od = 4*g+k;
      pgsh[(qd*8+g)*4+k] = zz0*u1w[od*2] + zz1*u1w[od*2+1] + u1b[od];
    }
  }
  __syncthreads();
  // --- pixel phase: 32 px (2 rows x 16 cols) x 8 slices (4 ch each) ---
  int p = tid & 31, sl = tid >> 5;
  int r = p>>4, c16 = p&15;
  int n = (2*ri + r)*96 + 16*cj + c16;
  int qd = c16>>1, kq = r*2 + (c16&1);
  float pg[8];
#pragma unroll
  for (int g=0;g<8;g++) pg[g] = pgsh[(qd*8+g)*4+kq];
  float xv[4]; float s=0.f,s2=0.f;
#pragma unroll
  for (int c=0;c<4;c++){
    int cc = sl*4+c;
    float a=u2b[cc];
#pragma unroll
    for (int g=0;g<8;g++) a+=pg[g]*u2w[cc*8+g];
    size_t off=((size_t)b*32+cc)*NP+n;
    float t = x[off]+a+cbuf[off]*y2sh[cc];
    xv[c]=t; xsum[off]=t; s+=t; s2+=t*t;
  }
  sred[0][sl][p]=s; sred[1][sl][p]=s2;
  __syncthreads();
  s=0.f; s2=0.f;
#pragma unroll
  for (int g=0;g<8;g++){ s += sred[0][g][p]; s2 += sred[1][g][p]; }
  float mu=s*(1.f/32.f), var=s2*(1.f/32.f)-mu*mu, rs=rsqrtf(var+1e-5f);
#pragma unroll
  for (int c=0;c<4;c++){
    int cc = sl*4+c;
    xsh[p][cc] = (xv[c]-mu)*rs*lw[cc]+lb[cc];
  }
  __syncthreads();
  float vv[32];
#pragma unroll
  for (int c=0;c<32;c++) vv[c]=xsh[p][c];
#pragma unroll
  for (int k=0;k<4;k++){
    int o = sl*4+k;
    float a=db1[o];
#pragma unroll
    for (int cc=0;cc<32;cc++) a+=vv[cc]*dw1[o*32+cc];
    d1[((size_t)b*32+o)*NP+n]=a;
  }
}

// K10: 7x7 depthwise conv (2 filters/channel), 2 vertical px/thread, + gate
__global__ __launch_bounds__(256) void k_dw(const float* __restrict__ d1,
    const float* __restrict__ w, const float* __restrict__ bias,
    float* __restrict__ dg)
{
  int idx = blockIdx.x*256+threadIdx.x;   // 64 planes * 4608
  int pl = idx/4608, n2 = idx%4608;
  int i2 = n2/96, j = n2%96;
  int c = pl&31;
  const float* dp = d1 + (size_t)pl*NP;
  const float* w0p = w + (2*c)*49;
  const float* w1p = w + (2*c+1)*49;
  float a0=bias[2*c], a1=bias[2*c+1];
  float c0=bias[2*c], c1=bias[2*c+1];
#pragma unroll
  for (int di=0;di<8;di++){
    int ii=2*i2-3+di; if ((unsigned)ii>=96u) continue;
    const float* rowp = dp + ii*96;
    float t[7];
#pragma unroll
    for (int dj=0;dj<7;dj++){
      int jj=j+dj-3;
      t[dj] = ((unsigned)jj<96u) ? rowp[jj] : 0.f;
    }
    if (di<7){
#pragma unroll
      for (int dj=0;dj<7;dj++){ a0 += t[dj]*w0p[di*7+dj]; a1 += t[dj]*w1p[di*7+dj]; }
    }
    if (di>0){
#pragma unroll
      for (int dj=0;dj<7;dj++){ c0 += t[dj]*w0p[(di-1)*7+dj]; c1 += t[dj]*w1p[(di-1)*7+dj]; }
    }
  }
  dg[(size_t)pl*NP + (size_t)(2*i2)*96 + j]   = gelu_ex(a0)*sigm(a1);
  dg[(size_t)pl*NP + (size_t)(2*i2+1)*96 + j] = gelu_ex(c0)*sigm(c1);
}

// K11: final 1x1 conv (32->32) + residual -> d_out. block = 32 px x 8 slices; grid 576
__global__ __launch_bounds__(256) void k_fin(const float* __restrict__ dg,
    const float* __restrict__ pw, const float* __restrict__ pb,
    const float* __restrict__ xsum, float* __restrict__ out)
{
  __shared__ float xsh[32][33];
  int p = threadIdx.x & 31, sl = threadIdx.x >> 5;
  int pix = blockIdx.x*32 + p;
  int b = pix/NP, n = pix%NP;
  const float* dp = dg + ((size_t)b*32 + sl*4)*NP + n;
#pragma unroll
  for (int c=0;c<4;c++) xsh[p][sl*4+c]=dp[(size_t)c*NP];
  __syncthreads();
  float vv[32];
#pragma unroll
  for (int c=0;c<32;c++) vv[c]=xsh[p][c];
#pragma unroll
  for (int k=0;k<4;k++){
    int o = sl*4+k;
    float a=pb[o];
#pragma unroll
    for (int cc=0;cc<32;cc++) a+=vv[cc]*pw[o*32+cc];
    size_t off=((size_t)b*32+o)*NP+n;
    out[off]=xsum[off]+a;
  }
}

extern "C" void kernel_launch(void* const* d_in, const int* in_sizes, int n_in,
                              void* d_out, int out_size, void* d_ws, size_t ws_size,
                              hipStream_t stream) {
  (void)in_sizes; (void)n_in; (void)out_size; (void)ws_size;
  const float* x       =(const float*)d_in[0];
  const float* cab_w1  =(const float*)d_in[1];
  const float* cab_w2  =(const float*)d_in[2];
  const float* cab_aw1 =(const float*)d_in[3];
  const float* cab_aw2 =(const float*)d_in[4];
  const float* sq1_w   =(const float*)d_in[5];
  const float* sq2_w   =(const float*)d_in[6];
  const float* ca_qkv_w=(const float*)d_in[7];
  const float* ca_fus_w=(const float*)d_in[8];
  const float* sa_qkv_w=(const float*)d_in[9];
  const float* sa_fus_w=(const float*)d_in[10];
  const float* un1_w   =(const float*)d_in[11];
  const float* un2_w   =(const float*)d_in[12];
  const float* da_w1   =(const float*)d_in[13];
  const float* da_dw_w =(const float*)d_in[14];
  const float* da_pw   =(const float*)d_in[15];
  const float* cab_b1  =(const float*)d_in[16];
  const float* cab_b2  =(const float*)d_in[17];
  const float* cab_ab1 =(const float*)d_in[18];
  const float* cab_ab2 =(const float*)d_in[19];
  const float* sq1_b   =(const float*)d_in[20];
  const float* sq2_b   =(const float*)d_in[21];
  const float* ca_qkv_b=(const float*)d_in[22];
  const float* ca_fus_b=(const float*)d_in[23];
  const float* sa_qkv_b=(const float*)d_in[24];
  const float* sa_fus_b=(const float*)d_in[25];
  const float* un1_b   =(const float*)d_in[26];
  const float* un2_b   =(const float*)d_in[27];
  const float* da_b1   =(const float*)d_in[28];
  const float* da_dw_b =(const float*)d_in[29];
  const float* da_pb   =(const float*)d_in[30];
  const float* ln1_w   =(const float*)d_in[31];
  const float* ln1_b   =(const float*)d_in[32];
  const float* ln2_w   =(const float*)d_in[33];
  const float* ln2_b   =(const float*)d_in[34];
  const float* ca_t    =(const float*)d_in[35];
  const float* sa_t    =(const float*)d_in[36];

  float* ws=(float*)d_ws;
  float* xn    = ws;               // 589824 (dead after phB; reused as d1)
  float* z1    = ws + 589824;      // 147456
  float* c1b   = ws + 737280;      // 147456
  float* cb    = ws + 884736;      // 589824 (cbuf; reused as dg after k_un2)
  float* u     = ws + 1474560;     // 73728
  float* xsm   = ws + 1548288;     // 589824
  float* ypart = ws + 2138112;     // 2304
  float* spart = ws + 2140416;     // 720 (+pad)
  float2* qarr = (float2*)(ws + 2141184);  // 32*2304*2 = 147456 floats
  float* mompart = ws + 2288640;   // 288*78 = 22464
  float* d1    = xn;               // alias: xn dead after phB
  float* dg    = cb;               // alias: cbuf dead after k_un2

  k_ln1 <<<576, 256,0,stream>>>(x, ln1_w, ln1_b, sq1_w, sq1_b, xn, z1);
  k_phB <<<720, 256,0,stream>>>(xn, cab_w1, cab_b1, z1, sq2_w, sq2_b, c1b, u, spart);
  k_phC <<<864, 256,0,stream>>>(c1b, cab_w2, cab_b2, cb, ypart,
                                u, spart, ca_qkv_w, ca_qkv_b, ca_t, ca_fus_w, ca_fus_b,
                                sa_qkv_w, sa_qkv_b, qarr, mompart);
  k_un2 <<<576, 256,0,stream>>>(mompart, qarr, sa_t, sa_qkv_w, sa_qkv_b,
                                sa_fus_w, sa_fus_b, un1_w, un1_b,
                                ypart, cab_aw1, cab_ab1, cab_aw2, cab_ab2,
                                un2_w, un2_b, x, cb, ln2_w, ln2_b, da_w1, da_b1, xsm, d1);
  k_dw  <<<1152,256,0,stream>>>(d1, da_dw_w, da_dw_b, dg);
  k_fin <<<576, 256,0,stream>>>(dg, da_pw, da_pb, xsm, (float*)d_out);
}

// Round 17
// 71.314 us; speedup vs baseline: 1.0413x; 1.0413x over previous
//
#include <hip/hip_runtime.h>
#include <cstdint>
#include <math.h>

#define NP 9216     // 96*96
#define NP2 2304    // 48*48
#define KH 12       // harmonics k=0..12 (I_13(1)~1e-12: exact in fp32)
#define NMOM 78     // 13 * 6

__device__ __forceinline__ float gelu_ex(float v){
  return 0.5f*v*(1.0f+erff(v*0.70710678118654752440f));
}
__device__ __forceinline__ float sigm(float v){
  return 1.0f/(1.0f+__expf(-v));
}

// K1: channel-LN over C=32 per pixel + sq1 1x1 conv (32->8)
// block = 32 px x 8 slices (4 ch each); grid = 576
__global__ __launch_bounds__(256) void k_ln1(const float* __restrict__ x,
    const float* __restrict__ lw, const float* __restrict__ lb,
    const float* __restrict__ sw, const float* __restrict__ sb,
    float* __restrict__ xn, float* __restrict__ z1)
{
  __shared__ float sred[2][8][32];
  __shared__ float xnsh[32][33];
  int p = threadIdx.x & 31, sl = threadIdx.x >> 5;
  int pix = blockIdx.x*32 + p;
  int b = pix / NP, n = pix % NP;
  const float* xp = x + (size_t)b*32*NP + (size_t)(sl*4)*NP + n;
  float v[4]; float s=0.f, s2=0.f;
#pragma unroll
  for (int c=0;c<4;c++){ float t=xp[(size_t)c*NP]; v[c]=t; s+=t; s2+=t*t; }
  sred[0][sl][p]=s; sred[1][sl][p]=s2;
  __syncthreads();
  s=0.f; s2=0.f;
#pragma unroll
  for (int g=0;g<8;g++){ s += sred[0][g][p]; s2 += sred[1][g][p]; }
  float mu = s*(1.f/32.f);
  float var = s2*(1.f/32.f)-mu*mu;
  float rs = rsqrtf(var+1e-5f);
  float* xo = xn + (size_t)b*32*NP + (size_t)(sl*4)*NP + n;
#pragma unroll
  for (int c=0;c<4;c++){
    int cc = sl*4+c;
    float t = (v[c]-mu)*rs*lw[cc]+lb[cc];
    xo[(size_t)c*NP] = t;
    xnsh[p][cc] = t;
  }
  __syncthreads();
  float vv[32];
#pragma unroll
  for (int c=0;c<32;c++) vv[c]=xnsh[p][c];
  int g = sl;
  float a = sb[g];
#pragma unroll
  for (int c=0;c<32;c++) a += vv[c]*sw[g*32+c];
  z1[(size_t)b*8*NP + (size_t)g*NP + n] = a;
}

// Phase B: cab1 (blocks 0..575, og-split 3x3 conv 32->8 + GELU)
//       || sq2  (blocks 576..719, stride-2 2x2 grouped conv + IDX permute + stats)
__global__ __launch_bounds__(256) void k_phB(const float* __restrict__ xn,
    const float* __restrict__ w1, const float* __restrict__ b1,
    const float* __restrict__ z1, const float* __restrict__ w2,
    const float* __restrict__ b2,
    float* __restrict__ c1, float* __restrict__ u, float* __restrict__ spart)
{
  if (blockIdx.x < 576){
    int og = blockIdx.x/72, pb = blockIdx.x%72;
    int idx = pb*256+threadIdx.x;
    int b = idx/NP, n = idx%NP, i = n/96, j = n%96;
    float acc = b1[og];
    const float* xb = xn + (size_t)b*32*NP;
    const float* wb = w1 + og*288;
#pragma unroll
    for (int di=0;di<3;di++){
      int ii=i+di-1; if ((unsigned)ii>=96u) continue;
#pragma unroll
      for (int dj=0;dj<3;dj++){
        int jj=j+dj-1; if ((unsigned)jj>=96u) continue;
        const float* xp = xb + ii*96+jj;
        const float* wp = wb + di*3+dj;
#pragma unroll
        for (int c=0;c<32;c++) acc += xp[(size_t)c*NP]*wp[c*9];
      }
    }
    c1[(size_t)b*8*NP + (size_t)og*NP + n] = gelu_ex(acc);
  } else {
    __shared__ float red[4][5];
    int u2 = blockIdx.x-576;
    int pr = u2/18, pb = u2%18;
    int idx = pb*256+threadIdx.x;
    int b = idx/NP2, n = idx%NP2, i = n/48, j = n%48;
    int ocA = pr, ocB = pr+8;           // cp = 2*pr, 2*pr+1
    int gA = ocA>>1, gB = ocB>>1;
    const float* zpA = z1 + ((size_t)b*8+gA)*NP + (size_t)(2*i)*96 + 2*j;
    const float* zpB = z1 + ((size_t)b*8+gB)*NP + (size_t)(2*i)*96 + 2*j;
    float vA = zpA[0]*w2[ocA*4]+zpA[1]*w2[ocA*4+1]+zpA[96]*w2[ocA*4+2]+zpA[97]*w2[ocA*4+3]+b2[ocA];
    float vB = zpB[0]*w2[ocB*4]+zpB[1]*w2[ocB*4+1]+zpB[96]*w2[ocB*4+2]+zpB[97]*w2[ocB*4+3]+b2[ocB];
    u[((size_t)b*16+2*pr)*NP2 + n]   = vA;
    u[((size_t)b*16+2*pr+1)*NP2 + n] = vB;
    int wv=threadIdx.x>>6, ln=threadIdx.x&63;
    float st[5]={vA,vB,vA*vA,vB*vB,vA*vB};
#pragma unroll
    for (int k=0;k<5;k++){
      float r=st[k];
#pragma unroll
      for (int m=1;m<64;m<<=1) r+=__shfl_xor(r,m,64);
      if (ln==0) red[wv][k]=r;
    }
    __syncthreads();
    if (threadIdx.x<5){
      float r = red[0][threadIdx.x]+red[1][threadIdx.x]+red[2][threadIdx.x]+red[3][threadIdx.x];
      spart[(b*9 + (pb%9))*40 + pr*5 + threadIdx.x] = r;
    }
  }
}

// Phase C: cab2 (blocks 0..575, og-split 3x3 conv 8->32 + SE partials)
//       || qkmom (blocks 576..863, q-hat + Fourier moments, inline coef collapse)
__global__ __launch_bounds__(256) void k_phC(const float* __restrict__ c1,
    const float* __restrict__ w2, const float* __restrict__ b2,
    float* __restrict__ cbuf, float* __restrict__ ypart,
    const float* __restrict__ u, const float* __restrict__ spart,
    const float* __restrict__ cqw, const float* __restrict__ cqb,
    const float* __restrict__ cat, const float* __restrict__ cfw,
    const float* __restrict__ cfb,
    const float* __restrict__ qw, const float* __restrict__ qb,
    float2* __restrict__ qarr, float* __restrict__ mompart)
{
  if (blockIdx.x < 576){
    __shared__ float red[4][4];
    int og = blockIdx.x/72, pb = blockIdx.x%72;
    int idx = pb*256+threadIdx.x;
    int b = idx/NP, n = idx%NP, i = n/96, j = n%96;
    float acc[4];
#pragma unroll
    for (int k=0;k<4;k++) acc[k]=b2[og*4+k];
    const float* cb = c1 + (size_t)b*8*NP;
#pragma unroll
    for (int di=0;di<3;di++){
      int ii=i+di-1; if ((unsigned)ii>=96u) continue;
#pragma unroll
      for (int dj=0;dj<3;dj++){
        int jj=j+dj-1; if ((unsigned)jj>=96u) continue;
        const float* xp = cb + ii*96+jj;
#pragma unroll
        for (int c=0;c<8;c++){
          float val = xp[(size_t)c*NP];
          const float* wp = w2 + (og*4)*72 + c*9+di*3+dj;
#pragma unroll
          for (int k=0;k<4;k++) acc[k] += val*wp[k*72];
        }
      }
    }
    int wv = threadIdx.x>>6, ln = threadIdx.x&63;
#pragma unroll
    for (int k=0;k<4;k++){
      cbuf[(size_t)b*32*NP + (size_t)(og*4+k)*NP + n] = acc[k];
      float r = acc[k];
#pragma unroll
      for (int m=1;m<64;m<<=1) r += __shfl_xor(r, m, 64);
      if (ln==0) red[wv][k]=r;
    }
    __syncthreads();
    if (threadIdx.x<4){
      float r = red[0][threadIdx.x]+red[1][threadIdx.x]+red[2][threadIdx.x]+red[3][threadIdx.x];
      ypart[(og*72+pb)*4 + threadIdx.x] = r;
    }
  } else {
    __shared__ float red16[16][80];
    int u2 = blockIdx.x-576;
    int bh = u2/9, ch = u2%9;
    int n = ch*256 + threadIdx.x;
    int b = bh>>4, h = bh&15;
    int p = h&7, s = h>>3;
    int cc0=2*p, cc1=2*p+1;
    int oc0 = 2*(cc0&7)+(cc0>>3);   // NIDX
    int oc1 = 2*(cc1&7)+(cc1>>3);
    float AA[2], BB[2], CCc[2];
#pragma unroll
    for (int t2=0;t2<2;t2++){
      int oc = t2? oc1:oc0;
      int p2 = oc>>1, dd = oc&1;
      float st[5]={0,0,0,0,0};
      for (int ib=0; ib<9; ib++){
#pragma unroll
        for (int k=0;k<5;k++) st[k] += spart[(b*9+ib)*40 + p2*5 + k];
      }
      float S0=st[0],S1=st[1],Q00=st[2],Q11=st[3],Q01=st[4];
      float Sd = dd? S1:S0;
      float Qdd = dd? Q11:Q00;
      float cu0[2],cu1[2],ccst[2];
#pragma unroll
      for (int hh=0;hh<2;hh++){
        int h2=p2+8*hh;
        float th2=cat[h2];
        float aq=cqw[(2*p2+dd)*6+hh], bq=cqb[(2*p2+dd)*6+hh];
        float nq=fmaxf(sqrtf(fmaxf(aq*aq*Qdd+2.f*aq*bq*Sd+2304.f*bq*bq,0.f)),1e-12f);
        float m2[2],av[2],bv[2];
#pragma unroll
        for (int e=0;e<2;e++){
          float Se_=e?S1:S0, Qee=e?Q11:Q00, Qde=(dd==e)?Qdd:Q01;
          float ak=cqw[(2*p2+e)*6+2+hh], bk=cqb[(2*p2+e)*6+2+hh];
          float nk=fmaxf(sqrtf(fmaxf(ak*ak*Qee+2.f*ak*bk*Se_+2304.f*bk*bk,0.f)),1e-12f);
          float D=aq*ak*Qde + aq*bk*Sd + bq*ak*Se_ + 2304.f*bq*bk;
          m2[e]=th2*D/(nq*nk);
          av[e]=cqw[(2*p2+e)*6+4+hh]; bv[e]=cqb[(2*p2+e)*6+4+hh];
        }
        float mx=fmaxf(m2[0],m2[1]);
        float e0=__expf(m2[0]-mx), e1=__expf(m2[1]-mx);
        float inv=1.f/(e0+e1);
        cu0[hh]=e0*inv*av[0]; cu1[hh]=e1*inv*av[1]; ccst[hh]=e0*inv*bv[0]+e1*inv*bv[1];
      }
      float f0=cfw[oc*2], f1=cfw[oc*2+1];
      AA[t2]=f0*cu0[0]+f1*cu0[1];
      BB[t2]=f0*cu1[0]+f1*cu1[1];
      CCc[t2]=f0*ccst[0]+f1*ccst[1]+cfb[oc];
    }
    const float* u00 = u + ((size_t)b*16 + (oc0>>1)*2)*NP2;
    const float* u01 = u00 + NP2;
    const float* u10 = u + ((size_t)b*16 + (oc1>>1)*2)*NP2;
    const float* u11 = u10 + NP2;
    float w0 = AA[0]*u00[n]+BB[0]*u01[n]+CCc[0];
    float w1 = AA[1]*u10[n]+BB[1]*u11[n]+CCc[1];
    float k0 = qw[cc0*6+2+s]*w0+qb[cc0*6+2+s];
    float k1 = qw[cc1*6+2+s]*w1+qb[cc1*6+2+s];
    float rnk = 1.f/fmaxf(sqrtf(k0*k0+k1*k1),1e-12f);
    float kc = k0*rnk, ks = k1*rnk;      // (cos beta, sin beta)
    float q0 = qw[cc0*6+s]*w0+qb[cc0*6+s];
    float q1 = qw[cc1*6+s]*w1+qb[cc1*6+s];
    float rnq = 1.f/fmaxf(sqrtf(q0*q0+q1*q1),1e-12f);
    qarr[bh*NP2+n] = make_float2(q0*rnq, q1*rnq);

    int grp = threadIdx.x>>4, gl = threadIdx.x&15;
    float c = 1.f, sn = 0.f;
#pragma unroll
    for (int k=0;k<=KH;k++){
      float vals[6] = {c, sn, c*w0, sn*w0, c*w1, sn*w1};
#pragma unroll
      for (int jv=0;jv<6;jv++){
        float r = vals[jv];
        r += __shfl_xor(r, 1, 64);
        r += __shfl_xor(r, 2, 64);
        r += __shfl_xor(r, 4, 64);
        r += __shfl_xor(r, 8, 64);
        if (gl==0) red16[grp][k*6+jv] = r;
      }
      float cn = c*kc - sn*ks;
      sn = sn*kc + c*ks;
      c = cn;
    }
    __syncthreads();
    if (threadIdx.x < NMOM){
      float r = 0.f;
#pragma unroll
      for (int g=0;g<16;g++) r += red16[g][threadIdx.x];
      mompart[(bh*9+ch)*NMOM + threadIdx.x] = r;
    }
  }
}

// K7: combine moment chunks, Bessel factors, per-row Fourier eval, softmax finish,
// v-affine, spat fuse conv, un1 grouped conv, pixel-shuffle write. grid 144.
__global__ __launch_bounds__(256) void k_rows(const float2* __restrict__ qarr,
    const float* __restrict__ mompart, const float* __restrict__ sat,
    const float* __restrict__ qw, const float* __restrict__ qb,
    const float* __restrict__ fw, const float* __restrict__ fb,
    const float* __restrict__ u1w, const float* __restrict__ u1b,
    float* __restrict__ ps)
{
  int bp = blockIdx.x/9, ch = blockIdx.x%9;
  int b = bp>>3, p = bp&7;
  int n = ch*256 + (int)threadIdx.x;
  __shared__ float msh[2][80];
  __shared__ float fsh[2][13];
  int tid = threadIdx.x;
  if (tid < 26){
    int hh = tid/13, k = tid%13;
    double t = (double)sat[p+8*hh];
    double fac;
    if (fabs(t) < 1e-3){
      double xh = 0.5*t;
      double pk = 1.0;
      for (int q=1;q<=k;q++) pk *= xh/(double)q;
      double Ik = pk*(1.0 + xh*xh/(double)(k+1));
      fac = (k? 2.0:1.0)*Ik;
    } else {
      const int KS = 36;
      double ip1 = 0.0, ik = 1e-280, sum2 = 0.0;
      double vk = 0.0, v0 = 0.0;
      for (int q=KS; q>=1; --q){
        if (q == k) vk = ik;
        sum2 += ik;
        double im1 = ip1 + (2.0*(double)q/t)*ik;
        ip1 = ik; ik = im1;
      }
      v0 = ik;
      if (k == 0) vk = v0;
      double total = v0 + 2.0*sum2;
      double scale = exp(t)/total;
      fac = (k? 2.0:1.0)*vk*scale;
    }
    fsh[hh][k] = (float)fac;
  }
  if (tid < 2*NMOM){
    int hh = tid/NMOM, jj = tid%NMOM;
    float ssum = 0.f;
    for (int ib=0; ib<9; ib++)
      ssum += mompart[((size_t)(b*16+p+8*hh)*9+ib)*NMOM + jj];
    msh[hh][jj] = ssum;
  }
  __syncthreads();
  if (tid < 2*NMOM){
    int hh = tid/NMOM, jj = tid%NMOM;
    msh[hh][jj] *= fsh[hh][jj/6];
  }
  __syncthreads();
  float o[2][2];
#pragma unroll
  for (int hh=0;hh<2;hh++){
    float2 q = qarr[(size_t)(b*16+p+8*hh)*NP2 + n];
    float c = 1.f, sn = 0.f;
    float Se=0.f, S0=0.f, S1=0.f;
#pragma unroll
    for (int k=0;k<=KH;k++){
      const float* mk = &msh[hh][k*6];
      Se += c*mk[0] + sn*mk[1];
      S0 += c*mk[2] + sn*mk[3];
      S1 += c*mk[4] + sn*mk[5];
      float cn = c*q.x - sn*q.y;
      sn = sn*q.x + c*q.y;
      c = cn;
    }
    float rSe = 1.f/Se;
    float av0=qw[(2*p)*6+4+hh],  bv0=qb[(2*p)*6+4+hh];
    float av1=qw[(2*p+1)*6+4+hh],bv1=qb[(2*p+1)*6+4+hh];
    o[hh][0]=av0*S0*rSe+bv0;
    o[hh][1]=av1*S1*rSe+bv1;
  }
  float zz0 = o[0][0]*fw[(2*p)*2]   + o[1][0]*fw[(2*p)*2+1]   + fb[2*p];
  float zz1 = o[0][1]*fw[(2*p+1)*2] + o[1][1]*fw[(2*p+1)*2+1] + fb[2*p+1];
  int i=n/48, j=n%48;
  float* pb2 = ps + ((size_t)b*8+p)*NP;
#pragma unroll
  for (int k=0;k<4;k++){
    int od = 4*p+k;
    float v = zz0*u1w[od*2] + zz1*u1w[od*2+1] + u1b[od];
    pb2[(size_t)(2*i+(k>>1))*96 + 2*j + (k&1)] = v;
  }
}

// K9: inline SE + un2 1x1 (8->32) + residual + LN2 + da_w1 1x1 (32->32)
// block = 32 px x 8 slices (4 ch each); grid = 576
__global__ __launch_bounds__(256) void k_un2(const float* __restrict__ ps,
    const float* __restrict__ ypart,
    const float* __restrict__ aw1, const float* __restrict__ ab1,
    const float* __restrict__ aw2, const float* __restrict__ ab2,
    const float* __restrict__ u2w, const float* __restrict__ u2b,
    const float* __restrict__ x, const float* __restrict__ cbuf,
    const float* __restrict__ lw, const float* __restrict__ lb,
    const float* __restrict__ dw1, const float* __restrict__ db1,
    float* __restrict__ xsum, float* __restrict__ d1)
{
  __shared__ float sred[2][8][32];
  __shared__ float xsh[32][33];
  __shared__ float y2sh[32];
  int p = threadIdx.x & 31, sl = threadIdx.x >> 5;
  int pix = blockIdx.x*32 + p;
  int b = pix/NP, n = pix%NP;
  if (threadIdx.x < 32){
    int c = threadIdx.x;
    float ssum = 0.f;
    for (int ib=0; ib<36; ib++)
      ssum += ypart[((c>>2)*72 + b*36 + ib)*4 + (c&3)];
    float pr = ssum*(1.f/9216.f)*aw1[c];
#pragma unroll
    for (int m=1;m<32;m<<=1) pr += __shfl_xor(pr, m, 64);
    float y1 = fmaxf(pr+ab1[0], 0.f);
    y2sh[c] = sigm(aw2[c]*y1+ab2[c]);
  }
  float pg[8];
#pragma unroll
  for (int g=0;g<8;g++) pg[g]=ps[((size_t)b*8+g)*NP+n];
  __syncthreads();
  float xv[4]; float s=0.f,s2=0.f;
#pragma unroll
  for (int c=0;c<4;c++){
    int cc = sl*4+c;
    float a=u2b[cc];
#pragma unroll
    for (int g=0;g<8;g++) a+=pg[g]*u2w[cc*8+g];
    size_t off=((size_t)b*32+cc)*NP+n;
    float t = x[off]+a+cbuf[off]*y2sh[cc];
    xv[c]=t; xsum[off]=t; s+=t; s2+=t*t;
  }
  sred[0][sl][p]=s; sred[1][sl][p]=s2;
  __syncthreads();
  s=0.f; s2=0.f;
#pragma unroll
  for (int g=0;g<8;g++){ s += sred[0][g][p]; s2 += sred[1][g][p]; }
  float mu=s*(1.f/32.f), var=s2*(1.f/32.f)-mu*mu, rs=rsqrtf(var+1e-5f);
#pragma unroll
  for (int c=0;c<4;c++){
    int cc = sl*4+c;
    xsh[p][cc] = (xv[c]-mu)*rs*lw[cc]+lb[cc];
  }
  __syncthreads();
  float vv[32];
#pragma unroll
  for (int c=0;c<32;c++) vv[c]=xsh[p][c];
#pragma unroll
  for (int k=0;k<4;k++){
    int o = sl*4+k;
    float a=db1[o];
#pragma unroll
    for (int cc=0;cc<32;cc++) a+=vv[cc]*dw1[o*32+cc];
    d1[((size_t)b*32+o)*NP+n]=a;
  }
}

// K10: 7x7 depthwise conv (2 filters/channel), 2 vertical px/thread, + gate
__global__ __launch_bounds__(256) void k_dw(const float* __restrict__ d1,
    const float* __restrict__ w, const float* __restrict__ bias,
    float* __restrict__ dg)
{
  int idx = blockIdx.x*256+threadIdx.x;   // 64 planes * 4608
  int pl = idx/4608, n2 = idx%4608;
  int i2 = n2/96, j = n2%96;
  int c = pl&31;
  const float* dp = d1 + (size_t)pl*NP;
  const float* w0p = w + (2*c)*49;
  const float* w1p = w + (2*c+1)*49;
  float a0=bias[2*c], a1=bias[2*c+1];
  float c0=bias[2*c], c1=bias[2*c+1];
#pragma unroll
  for (int di=0;di<8;di++){
    int ii=2*i2-3+di; if ((unsigned)ii>=96u) continue;
    const float* rowp = dp + ii*96;
    float t[7];
#pragma unroll
    for (int dj=0;dj<7;dj++){
      int jj=j+dj-3;
      t[dj] = ((unsigned)jj<96u) ? rowp[jj] : 0.f;
    }
    if (di<7){
#pragma unroll
      for (int dj=0;dj<7;dj++){ a0 += t[dj]*w0p[di*7+dj]; a1 += t[dj]*w1p[di*7+dj]; }
    }
    if (di>0){
#pragma unroll
      for (int dj=0;dj<7;dj++){ c0 += t[dj]*w0p[(di-1)*7+dj]; c1 += t[dj]*w1p[(di-1)*7+dj]; }
    }
  }
  dg[(size_t)pl*NP + (size_t)(2*i2)*96 + j]   = gelu_ex(a0)*sigm(a1);
  dg[(size_t)pl*NP + (size_t)(2*i2+1)*96 + j] = gelu_ex(c0)*sigm(c1);
}

// K11: final 1x1 conv (32->32) + residual -> d_out. block = 32 px x 8 slices; grid 576
__global__ __launch_bounds__(256) void k_fin(const float* __restrict__ dg,
    const float* __restrict__ pw, const float* __restrict__ pb,
    const float* __restrict__ xsum, float* __restrict__ out)
{
  __shared__ float xsh[32][33];
  int p = threadIdx.x & 31, sl = threadIdx.x >> 5;
  int pix = blockIdx.x*32 + p;
  int b = pix/NP, n = pix%NP;
  const float* dp = dg + ((size_t)b*32 + sl*4)*NP + n;
#pragma unroll
  for (int c=0;c<4;c++) xsh[p][sl*4+c]=dp[(size_t)c*NP];
  __syncthreads();
  float vv[32];
#pragma unroll
  for (int c=0;c<32;c++) vv[c]=xsh[p][c];
#pragma unroll
  for (int k=0;k<4;k++){
    int o = sl*4+k;
    float a=pb[o];
#pragma unroll
    for (int cc=0;cc<32;cc++) a+=vv[cc]*pw[o*32+cc];
    size_t off=((size_t)b*32+o)*NP+n;
    out[off]=xsum[off]+a;
  }
}

extern "C" void kernel_launch(void* const* d_in, const int* in_sizes, int n_in,
                              void* d_out, int out_size, void* d_ws, size_t ws_size,
                              hipStream_t stream) {
  (void)in_sizes; (void)n_in; (void)out_size; (void)ws_size;
  const float* x       =(const float*)d_in[0];
  const float* cab_w1  =(const float*)d_in[1];
  const float* cab_w2  =(const float*)d_in[2];
  const float* cab_aw1 =(const float*)d_in[3];
  const float* cab_aw2 =(const float*)d_in[4];
  const float* sq1_w   =(const float*)d_in[5];
  const float* sq2_w   =(const float*)d_in[6];
  const float* ca_qkv_w=(const float*)d_in[7];
  const float* ca_fus_w=(const float*)d_in[8];
  const float* sa_qkv_w=(const float*)d_in[9];
  const float* sa_fus_w=(const float*)d_in[10];
  const float* un1_w   =(const float*)d_in[11];
  const float* un2_w   =(const float*)d_in[12];
  const float* da_w1   =(const float*)d_in[13];
  const float* da_dw_w =(const float*)d_in[14];
  const float* da_pw   =(const float*)d_in[15];
  const float* cab_b1  =(const float*)d_in[16];
  const float* cab_b2  =(const float*)d_in[17];
  const float* cab_ab1 =(const float*)d_in[18];
  const float* cab_ab2 =(const float*)d_in[19];
  const float* sq1_b   =(const float*)d_in[20];
  const float* sq2_b   =(const float*)d_in[21];
  const float* ca_qkv_b=(const float*)d_in[22];
  const float* ca_fus_b=(const float*)d_in[23];
  const float* sa_qkv_b=(const float*)d_in[24];
  const float* sa_fus_b=(const float*)d_in[25];
  const float* un1_b   =(const float*)d_in[26];
  const float* un2_b   =(const float*)d_in[27];
  const float* da_b1   =(const float*)d_in[28];
  const float* da_dw_b =(const float*)d_in[29];
  const float* da_pb   =(const float*)d_in[30];
  const float* ln1_w   =(const float*)d_in[31];
  const float* ln1_b   =(const float*)d_in[32];
  const float* ln2_w   =(const float*)d_in[33];
  const float* ln2_b   =(const float*)d_in[34];
  const float* ca_t    =(const float*)d_in[35];
  const float* sa_t    =(const float*)d_in[36];

  float* ws=(float*)d_ws;
  float* xn    = ws;               // 589824 (dead after phB; reused as d1)
  float* z1    = ws + 589824;      // 147456
  float* c1b   = ws + 737280;      // 147456
  float* cb    = ws + 884736;      // 589824 (cbuf; reused as dg after k_un2)
  float* u     = ws + 1474560;     // 73728
  float* psb   = ws + 1548288;     // 147456
  float* xsm   = ws + 1695744;     // 589824
  float* ypart = ws + 2285568;     // 2304
  float* spart = ws + 2287872;     // 720 (+pad)
  float2* qarr = (float2*)(ws + 2288640);  // 32*2304*2 = 147456 floats
  float* mompart = ws + 2436096;   // 288*78 = 22464
  float* d1    = xn;               // alias: xn dead after phB
  float* dg    = cb;               // alias: cbuf dead after k_un2

  k_ln1 <<<576, 256,0,stream>>>(x, ln1_w, ln1_b, sq1_w, sq1_b, xn, z1);
  k_phB <<<720, 256,0,stream>>>(xn, cab_w1, cab_b1, z1, sq2_w, sq2_b, c1b, u, spart);
  k_phC <<<864, 256,0,stream>>>(c1b, cab_w2, cab_b2, cb, ypart,
                                u, spart, ca_qkv_w, ca_qkv_b, ca_t, ca_fus_w, ca_fus_b,
                                sa_qkv_w, sa_qkv_b, qarr, mompart);
  k_rows<<<144, 256,0,stream>>>(qarr, mompart, sa_t, sa_qkv_w, sa_qkv_b,
                                sa_fus_w, sa_fus_b, un1_w, un1_b, psb);
  k_un2 <<<576, 256,0,stream>>>(psb, ypart, cab_aw1, cab_ab1, cab_aw2, cab_ab2,
                                un2_w, un2_b, x, cb, ln2_w, ln2_b, da_w1, da_b1, xsm, d1);
  k_dw  <<<1152,256,0,stream>>>(d1, da_dw_w, da_dw_b, dg);
  k_fin <<<576, 256,0,stream>>>(dg, da_pw, da_pb, xsm, (float*)d_out);
}